// Round 12
// baseline (371.167 us; speedup 1.0000x reference)
//
#include <hip/hip_runtime.h>
#include <math.h>

// KGVAE: 2-layer RelGraphConv (bdd) + reparameterize, R12.
// Column-split edge kernels: two waves per node (half h computes half the
// output columns) -> halved per-wave serial chain, doubled wave count.
// Edge meta packed uint2 {src|rel<<16, norm}. MFMA self-loop GEMMs (R11).
// ws: h1bh | h1h | h2bh | embh | w1h | w2h | emA | emB | deg fil | off | bsum

typedef __attribute__((ext_vector_type(8))) short bf16x8;
typedef __attribute__((ext_vector_type(4))) float f32x4;
typedef __attribute__((ext_vector_type(2))) float v2f;

__device__ __forceinline__ int bcasti(int v, int l) {
    return __builtin_amdgcn_readlane(v, l);
}
__device__ __forceinline__ float bcastf(float v, int l) {
    return __int_as_float(__builtin_amdgcn_readlane(__float_as_int(v), l));
}
__device__ __forceinline__ unsigned short f2bf(float f) {  // RTN bf16
    unsigned u = __float_as_uint(f);
    return (unsigned short)((u + 0x7FFFu + ((u >> 16) & 1u)) >> 16);
}
__device__ __forceinline__ float bfs(unsigned short s) { return __uint_as_float((unsigned)s << 16); }
__device__ __forceinline__ v2f bf2(unsigned u) {  // 2 packed bf16 -> float2
    v2f r;
    r.x = __uint_as_float(u << 16);
    r.y = __uint_as_float(u & 0xFFFF0000u);
    return r;
}

__global__ void hist(const int* __restrict__ dst, int* __restrict__ deg, int e) {
    int i = blockIdx.x * blockDim.x + threadIdx.x;
    if (i < e) atomicAdd(&deg[dst[i]], 1);
}

__global__ void scan_part(const int* __restrict__ deg, int* __restrict__ bsum, int n) {
    __shared__ int sm[256];
    int t = threadIdx.x, g = blockIdx.x * 256 + t;
    sm[t] = (g < n) ? deg[g] : 0;
    __syncthreads();
    for (int d = 128; d > 0; d >>= 1) {
        if (t < d) sm[t] += sm[t + d];
        __syncthreads();
    }
    if (t == 0) bsum[blockIdx.x] = sm[0];
}

__global__ void scan_bsum(int* __restrict__ bsum, int* __restrict__ off, int nb, int n) {
    __shared__ int sm[256];
    int t = threadIdx.x;
    int v = (t < nb) ? bsum[t] : 0;
    sm[t] = v;
    __syncthreads();
    for (int d = 1; d < 256; d <<= 1) {
        int u = (t >= d) ? sm[t - d] : 0;
        __syncthreads();
        sm[t] += u;
        __syncthreads();
    }
    if (t < nb) bsum[t] = sm[t] - v;
    if (t == 255) off[n] = sm[255];
}

__global__ void scan_write(const int* __restrict__ deg, const int* __restrict__ bsum,
                           int* __restrict__ off, int n) {
    __shared__ int sm[256];
    int t = threadIdx.x, g = blockIdx.x * 256 + t;
    int v = (g < n) ? deg[g] : 0;
    sm[t] = v;
    __syncthreads();
    for (int d = 1; d < 256; d <<= 1) {
        int u = (t >= d) ? sm[t - d] : 0;
        __syncthreads();
        sm[t] += u;
        __syncthreads();
    }
    if (g < n) off[g] = bsum[blockIdx.x] + sm[t] - v;
}

// emA = {h_ids[src]|rel<<16, norm}; emB = {src|rel<<16, norm}
__global__ void scatter_pack(const int* __restrict__ src, const int* __restrict__ dst,
                             const int* __restrict__ rel, const float* __restrict__ norm,
                             const int* __restrict__ h_ids, const int* __restrict__ off,
                             int* __restrict__ fil, uint2* __restrict__ emA,
                             uint2* __restrict__ emB, int e) {
    int i = blockIdx.x * blockDim.x + threadIdx.x;
    if (i >= e) return;
    int d = dst[i];
    int p = off[d] + atomicAdd(&fil[d], 1);
    unsigned rhi = (unsigned)rel[i] << 16;
    int s = src[i];
    unsigned nb = __float_as_uint(norm[i]);
    emA[p] = make_uint2((unsigned)h_ids[s] | rhi, nb);
    emB[p] = make_uint2((unsigned)s | rhi, nb);
}

// fused bf16 conversion: w1, w2, emb
__global__ void cvt_all(const float* __restrict__ w1, const float* __restrict__ w2,
                        const float* __restrict__ emb, unsigned short* __restrict__ w1h,
                        unsigned short* __restrict__ w2h, unsigned short* __restrict__ embh,
                        int n1, int n2, int ne) {
    int i = blockIdx.x * blockDim.x + threadIdx.x;
    if (i < n1) w1h[i] = f2bf(w1[i]);
    else if (i < n1 + n2) w2h[i - n1] = f2bf(w2[i - n1]);
    else if (i < n1 + n2 + ne) embh[i - n1 - n2] = f2bf(emb[i - n1 - n2]);
}

// gemm1: h1bh[16-row tile] = bf16(b1 + embh[h_ids[row]] @ bf16(lw1))   (MFMA)
__global__ __launch_bounds__(256) void
gemm1_mfma(const unsigned short* __restrict__ embh, const int* __restrict__ h_ids,
           const float* __restrict__ lw1, const float* __restrict__ b1,
           unsigned short* __restrict__ h1bh, int n_nodes) {
    int w = threadIdx.x >> 6, l = threadIdx.x & 63;
    int lr = l & 15, lq = l >> 4;
    int rt = blockIdx.x;
    bf16x8 bfr[2];
    int coln = w * 16 + lr;
#pragma unroll
    for (int kb = 0; kb < 2; ++kb)
#pragma unroll
        for (int jj = 0; jj < 8; ++jj)
            bfr[kb][jj] = (short)f2bf(lw1[(kb * 32 + lq * 8 + jj) * 64 + coln]);
    int nrow = rt * 16 + lr;
    if (nrow >= n_nodes) nrow = n_nodes - 1;
    const unsigned short* arow = embh + (long)h_ids[nrow] * 64 + lq * 8;
    bf16x8 af0 = *(const bf16x8*)arow;
    bf16x8 af1 = *(const bf16x8*)(arow + 32);
    f32x4 acc = {0.f, 0.f, 0.f, 0.f};
    acc = __builtin_amdgcn_mfma_f32_16x16x32_bf16(af0, bfr[0], acc, 0, 0, 0);
    acc = __builtin_amdgcn_mfma_f32_16x16x32_bf16(af1, bfr[1], acc, 0, 0, 0);
    float bb = b1[coln];
#pragma unroll
    for (int r = 0; r < 4; ++r) {
        int row = rt * 16 + lq * 4 + r;
        if (row < n_nodes) h1bh[(long)row * 64 + coln] = f2bf(acc[r] + bb);
    }
}

// gemm2: h2bh[16-row tile] = bf16(b2 + h1h @ bf16(lw2))  (MFMA)
__global__ __launch_bounds__(256) void
gemm2_mfma(const unsigned short* __restrict__ h1h, const float* __restrict__ lw2,
           const float* __restrict__ b2, unsigned short* __restrict__ h2bh, int n_nodes) {
    int w = threadIdx.x >> 6, l = threadIdx.x & 63;
    int lr = l & 15, lq = l >> 4;
    int rt = blockIdx.x;
    bf16x8 bfr[2][2];
    int col0 = (2 * w) * 16 + lr, col1 = (2 * w + 1) * 16 + lr;
#pragma unroll
    for (int kb = 0; kb < 2; ++kb)
#pragma unroll
        for (int jj = 0; jj < 8; ++jj) {
            int k = kb * 32 + lq * 8 + jj;
            bfr[0][kb][jj] = (short)f2bf(lw2[k * 128 + col0]);
            bfr[1][kb][jj] = (short)f2bf(lw2[k * 128 + col1]);
        }
    int nrow = rt * 16 + lr;
    if (nrow >= n_nodes) nrow = n_nodes - 1;
    bf16x8 af0 = *(const bf16x8*)(h1h + (long)nrow * 64 + lq * 8);
    bf16x8 af1 = *(const bf16x8*)(h1h + (long)nrow * 64 + 32 + lq * 8);
    f32x4 acc0 = {0.f, 0.f, 0.f, 0.f}, acc1 = {0.f, 0.f, 0.f, 0.f};
    acc0 = __builtin_amdgcn_mfma_f32_16x16x32_bf16(af0, bfr[0][0], acc0, 0, 0, 0);
    acc0 = __builtin_amdgcn_mfma_f32_16x16x32_bf16(af1, bfr[0][1], acc0, 0, 0, 0);
    acc1 = __builtin_amdgcn_mfma_f32_16x16x32_bf16(af0, bfr[1][0], acc1, 0, 0, 0);
    acc1 = __builtin_amdgcn_mfma_f32_16x16x32_bf16(af1, bfr[1][1], acc1, 0, 0, 0);
    float bb0 = b2[col0], bb1 = b2[col1];
#pragma unroll
    for (int r = 0; r < 4; ++r) {
        int row = rt * 16 + lq * 4 + r;
        if (row < n_nodes) {
            h2bh[(long)row * 128 + col0] = f2bf(acc0[r] + bb0);
            h2bh[(long)row * 128 + col1] = f2bf(acc1[r] + bb1);
        }
    }
}

// butterfly transpose-reduce over 8-lane group
__device__ __forceinline__ float reduce8(float a0, float a1, float a2, float a3,
                                         float a4, float a5, float a6, float a7, int i) {
    int p1 = i & 1, p2 = (i >> 1) & 1, p3 = (i >> 2) & 1;
    float ka, sb, u0, u1, u2, u3, w0, w1;
    ka = p1 ? a1 : a0; sb = p1 ? a0 : a1; u0 = ka + __shfl_xor(sb, 1, 64);
    ka = p1 ? a3 : a2; sb = p1 ? a2 : a3; u1 = ka + __shfl_xor(sb, 1, 64);
    ka = p1 ? a5 : a4; sb = p1 ? a4 : a5; u2 = ka + __shfl_xor(sb, 1, 64);
    ka = p1 ? a7 : a6; sb = p1 ? a6 : a7; u3 = ka + __shfl_xor(sb, 1, 64);
    ka = p2 ? u1 : u0; sb = p2 ? u0 : u1; w0 = ka + __shfl_xor(sb, 2, 64);
    ka = p2 ? u3 : u2; sb = p2 ? u2 : u3; w1 = ka + __shfl_xor(sb, 2, 64);
    ka = p3 ? w1 : w0; sb = p3 ? w0 : w1;
    return ka + __shfl_xor(sb, 4, 64);
}

// edge1 (column-split): wave (n,h) computes cols b*8 + h*4 + {0..3}
__global__ __launch_bounds__(256) void
edge1(const unsigned short* __restrict__ embh, const unsigned short* __restrict__ w1h,
      const unsigned short* __restrict__ h1bh, const int* __restrict__ off,
      const uint2* __restrict__ emA, unsigned short* __restrict__ h1h, int n_nodes) {
    int tid = threadIdx.x;
    int w = tid >> 6, j = tid & 63, i = j & 7;
    int wg = blockIdx.x * 4 + w;
    int n = wg >> 1, h = wg & 1;
    if (n >= n_nodes) return;
    const long woff = (long)j * 8 + h * 4;  // bf16 elems: b*64 + i*8 + h*4
    v2f acc01 = {0.f, 0.f}, acc23 = {0.f, 0.f};
    int e0 = off[n], e1v = off[n + 1];
    for (int win = e0; win < e1v; win += 64) {
        int wcnt = e1v - win; if (wcnt > 64) wcnt = 64;
        uint2 mv = (j < wcnt) ? emA[win + j] : make_uint2(0u, 0u);
        float nmf = __uint_as_float(mv.y);
        for (int b16 = 0; b16 < wcnt; b16 += 16) {
            int cnt = wcnt - b16; if (cnt > 16) cnt = 16;
            float xs[16];
            int rr[16];
#pragma unroll
            for (int c = 0; c < 16; ++c)
                if (c < cnt) {
                    int uc = bcasti((int)mv.x, b16 + c);
                    xs[c] = bfs(embh[(long)(uc & 0xFFFF) * 64 + j]);
                    rr[c] = uc >> 16;
                }
#pragma unroll
            for (int c = 0; c < 16; ++c)
                if (c < cnt) {
                    float nm = bcastf(nmf, b16 + c);
                    uint2 wd = *(const uint2*)(w1h + (long)rr[c] * 512 + woff);
                    float xm = xs[c] * nm;
                    v2f xm2 = {xm, xm};
                    acc01 += xm2 * bf2(wd.x);
                    acc23 += xm2 * bf2(wd.y);
                }
        }
    }
    float agg = reduce8(acc01.x, acc01.y, acc23.x, acc23.y, 0.f, 0.f, 0.f, 0.f, i);
    if (i < 4) {
        int col = (j & 56) + h * 4 + i;   // b*8 + h*4 + i
        long p = (long)n * 64 + col;
        float base = bfs(h1bh[p]);
        h1h[p] = f2bf(fmaxf(base + agg, 0.f));
    }
}

// edge2 (column-split): wave (n,h) computes cols b*16 + h*8 + {0..7}; fused reparam
__global__ __launch_bounds__(256) void
edge2(const unsigned short* __restrict__ h1h, const unsigned short* __restrict__ w2h,
      const unsigned short* __restrict__ h2bh, const float* __restrict__ eps,
      const int* __restrict__ off, const uint2* __restrict__ emB,
      float* __restrict__ out, int n_nodes) {
    int tid = threadIdx.x;
    int w = tid >> 6, j = tid & 63, i = j & 7;
    int wg = blockIdx.x * 4 + w;
    int n = wg >> 1, h = wg & 1;
    if (n >= n_nodes) return;
    const long woff = (long)j * 16 + h * 8;  // bf16 elems: b*128 + i*16 + h*8
    v2f acc[4];
#pragma unroll
    for (int q = 0; q < 4; ++q) acc[q] = (v2f){0.f, 0.f};
    int e0 = off[n], e1v = off[n + 1];
    for (int win = e0; win < e1v; win += 64) {
        int wcnt = e1v - win; if (wcnt > 64) wcnt = 64;
        uint2 mv = (j < wcnt) ? emB[win + j] : make_uint2(0u, 0u);
        float nmf = __uint_as_float(mv.y);
        for (int b16 = 0; b16 < wcnt; b16 += 16) {
            int cnt = wcnt - b16; if (cnt > 16) cnt = 16;
            float xs[16];
            int rr[16];
#pragma unroll
            for (int c = 0; c < 16; ++c)
                if (c < cnt) {
                    int uc = bcasti((int)mv.x, b16 + c);
                    xs[c] = bfs(h1h[(long)(uc & 0xFFFF) * 64 + j]);
                    rr[c] = uc >> 16;
                }
#pragma unroll
            for (int c = 0; c < 16; ++c)
                if (c < cnt) {
                    float nm = bcastf(nmf, b16 + c);
                    uint4 wd = *(const uint4*)(w2h + (long)rr[c] * 1024 + woff);
                    float xm = xs[c] * nm;
                    v2f xm2 = {xm, xm};
                    acc[0] += xm2 * bf2(wd.x);
                    acc[1] += xm2 * bf2(wd.y);
                    acc[2] += xm2 * bf2(wd.z);
                    acc[3] += xm2 * bf2(wd.w);
                }
        }
    }
    float r = reduce8(acc[0].x, acc[0].y, acc[1].x, acc[1].y,
                      acc[2].x, acc[2].y, acc[3].x, acc[3].y, i);
    int o = (j & 56) * 2 + h * 8 + i;   // b*16 + h*8 + i
    float base = bfs(h2bh[(long)n * 128 + o]);
    float v = r + base;
    float p = __shfl_xor(v, 32, 64);   // partner col o+64 (b+4)
    if (j < 32) {                       // b<4 -> o<64: m col, partner is raw_v
        long basep = (long)n * 64 + o;
        float sp = (p > 20.f) ? p : log1pf(expf(p));
        out[basep] = fmaf(sqrtf(sp + 1e-8f), eps[basep], v);
    }
}

extern "C" void kernel_launch(void* const* d_in, const int* in_sizes, int n_in,
                              void* d_out, int out_size, void* d_ws, size_t ws_size,
                              hipStream_t stream) {
    const float* emb   = (const float*)d_in[0];
    const float* norm  = (const float*)d_in[1];
    const float* eps   = (const float*)d_in[2];
    const float* w1    = (const float*)d_in[3];
    const float* lw1   = (const float*)d_in[4];
    const float* b1    = (const float*)d_in[5];
    const float* w2    = (const float*)d_in[6];
    const float* lw2   = (const float*)d_in[7];
    const float* b2    = (const float*)d_in[8];
    const int*   h_ids = (const int*)d_in[9];
    const int*   src   = (const int*)d_in[10];
    const int*   dst   = (const int*)d_in[11];
    const int*   rel   = (const int*)d_in[12];
    float* out = (float*)d_out;

    int n_nodes = in_sizes[0] / 64;   // 50000
    int n_edges = in_sizes[10];       // 400000
    int nw1 = in_sizes[3];            // 200*512
    int nw2 = in_sizes[6];            // 200*1024
    int ne  = in_sizes[0];            // N*64

    char* ws = (char*)d_ws;
    unsigned short* h1bh = (unsigned short*)ws;       ws += (size_t)n_nodes * 64 * 2;
    unsigned short* h1h  = (unsigned short*)ws;       ws += (size_t)n_nodes * 64 * 2;
    unsigned short* h2bh = (unsigned short*)ws;       ws += (size_t)n_nodes * 128 * 2;
    unsigned short* embh = (unsigned short*)ws;       ws += (size_t)ne * 2;
    unsigned short* w1h  = (unsigned short*)ws;       ws += (size_t)nw1 * 2;
    unsigned short* w2h  = (unsigned short*)ws;       ws += (size_t)nw2 * 2;
    uint2* emA    = (uint2*)ws;                       ws += (size_t)n_edges * 8;
    uint2* emB    = (uint2*)ws;                       ws += (size_t)n_edges * 8;
    int*   deg    = (int*)ws;                         ws += (size_t)n_nodes * 4;
    int*   fil    = (int*)ws;                         ws += (size_t)n_nodes * 4;
    int*   off    = (int*)ws;                         ws += (size_t)(n_nodes + 1) * 4;
    int*   bsum   = (int*)ws;

    int blk = 256;
    int nb = (n_nodes + 255) / 256;
    int nt = (n_nodes + 15) / 16;
    int egrid = (n_nodes * 2 + 3) / 4;   // 2 halves per node, 4 waves/block
    // CSR build + bf16 conversions
    hipMemsetAsync(deg, 0, (size_t)n_nodes * 8, stream);
    cvt_all<<<(nw1 + nw2 + ne + blk - 1) / blk, blk, 0, stream>>>(w1, w2, emb, w1h, w2h, embh, nw1, nw2, ne);
    hist<<<(n_edges + blk - 1) / blk, blk, 0, stream>>>(dst, deg, n_edges);
    scan_part<<<nb, 256, 0, stream>>>(deg, bsum, n_nodes);
    scan_bsum<<<1, 256, 0, stream>>>(bsum, off, nb, n_nodes);
    scan_write<<<nb, 256, 0, stream>>>(deg, bsum, off, n_nodes);
    scatter_pack<<<(n_edges + blk - 1) / blk, blk, 0, stream>>>(src, dst, rel, norm, h_ids, off, fil, emA, emB, n_edges);
    // layer 1
    gemm1_mfma<<<nt, blk, 0, stream>>>(embh, h_ids, lw1, b1, h1bh, n_nodes);
    edge1<<<egrid, blk, 0, stream>>>(embh, w1h, h1bh, off, emA, h1h, n_nodes);
    // layer 2
    gemm2_mfma<<<nt, blk, 0, stream>>>(h1h, lw2, b2, h2bh, n_nodes);
    edge2<<<egrid, blk, 0, stream>>>(h1h, w2h, h2bh, eps, off, emB, out, n_nodes);
}